// Round 1
// baseline (454.678 us; speedup 1.0000x reference)
//
#include <hip/hip_runtime.h>
#include <hip/hip_bf16.h>
#include <stdint.h>

#define S_LEN 2048
#define B_SZ  16
#define D_DIM 1024
#define H_DIM 1024
#define M_TOT (S_LEN * B_SZ)      // 32768
#define N_TOT (3 * H_DIM)         // 3072
#define K_TOT D_DIM               // 1024

#define BM 128
#define BN 128
#define BK 32
#define KSTEPS (K_TOT / BK)       // 32
#define NTN (N_TOT / BN)          // 24
#define NWG ((M_TOT / BM) * NTN)  // 6144

#define NCHUNK 32
#define CLEN   64                 // NCHUNK*CLEN == S_LEN
#define NCH    (B_SZ * H_DIM)     // 16384 independent channels

typedef __attribute__((ext_vector_type(8))) short short8;
typedef __attribute__((ext_vector_type(4))) float f32x4;

// ---------- helpers ----------
__device__ __forceinline__ void gload_lds16(const void* g, void* l) {
  __builtin_amdgcn_global_load_lds((__attribute__((address_space(1))) void*)g,
                                   (__attribute__((address_space(3))) void*)l,
                                   16, 0, 0);
}

__device__ __forceinline__ unsigned short f2bfbits(float x) {
  union { __hip_bfloat16 h; unsigned short u; } cv;
  cv.h = __float2bfloat16(x);
  return cv.u;
}

__device__ __forceinline__ float sigmoidf_fast(float y) {
  return 1.f / (1.f + __expf(-y));
}

__device__ __forceinline__ float tanhf_fast(float y) {
  float ay = fabsf(y);
  float e  = __expf(-2.f * ay);
  float t  = (1.f - e) / (1.f + e);
  return copysignf(t, y);
}

// ---------- fp32 -> bf16 conversion (vectorized) ----------
__global__ void cvt_kernel(const float* __restrict__ in,
                           unsigned short* __restrict__ out, int n4) {
  int i = blockIdx.x * 256 + threadIdx.x;
  if (i < n4) {
    float4 v = ((const float4*)in)[i];
    ushort4 o;
    o.x = f2bfbits(v.x); o.y = f2bfbits(v.y);
    o.z = f2bfbits(v.z); o.w = f2bfbits(v.w);
    ((ushort4*)out)[i] = o;
  }
}

// ---------- GEMM (m97 structure): Y = Xb * Wb^T + bias, fused activations ----------
// Xb: [M,K] bf16 row-major. Wb: [N,K] bf16 row-major (B^T input). Output per 1024-col chunk:
// chunk0 -> Z=tanh (bf16 ws), chunk1 -> F=sigmoid (bf16 ws), chunk2 -> sigO=sigmoid (bf16 ws)
__global__ __launch_bounds__(256) void gemm_act(
    const __hip_bfloat16* __restrict__ Xb,
    const __hip_bfloat16* __restrict__ Wb,
    const float* __restrict__ bias,
    unsigned short* __restrict__ wsZ,
    unsigned short* __restrict__ wsF,
    unsigned short* __restrict__ wsO) {
  __shared__ __align__(16) short As[BM * BK];  // [128][32] bf16, 64B row stride
  __shared__ __align__(16) short Bs[BN * BK];

  // XCD-aware swizzle (NWG % 8 == 0 -> simple bijective form)
  int bid = blockIdx.x;
  int swz = (bid & 7) * (NWG >> 3) + (bid >> 3);
  int tm  = swz / NTN;
  int tn  = swz - tm * NTN;
  const int m0 = tm * BM;
  const int n0 = tn * BN;

  const int tid  = threadIdx.x;
  const int lane = tid & 63;
  const int w    = tid >> 6;
  const int wm   = (w >> 1) << 6;   // wave row offset in tile
  const int wn   = (w & 1) << 6;    // wave col offset in tile
  const int lr   = lane & 15;
  const int lg   = lane >> 4;

  // staging coords: thread t covers 16B; row = t/4, byte-in-row = (t%4)*16
  const int srow = tid >> 2;
  const int skb  = (tid & 3) << 4;

  const char* Abase = (const char*)(Xb + (size_t)m0 * K_TOT);
  const char* Bbase = (const char*)(Wb + (size_t)n0 * K_TOT);

  f32x4 acc[4][4];
  const f32x4 vzero = {0.f, 0.f, 0.f, 0.f};
  #pragma unroll
  for (int i = 0; i < 4; ++i)
    #pragma unroll
    for (int j = 0; j < 4; ++j) acc[i][j] = vzero;

  for (int kt = 0; kt < KSTEPS; ++kt) {
    if (kt) __syncthreads();  // previous iter's LDS reads complete
    const size_t kb = (size_t)kt * (BK * 2) + skb;  // byte offset along K
    gload_lds16(Abase + (size_t)srow        * (K_TOT * 2) + kb, (char*)As + srow * 64 + skb);
    gload_lds16(Abase + (size_t)(srow + 64) * (K_TOT * 2) + kb, (char*)As + (srow + 64) * 64 + skb);
    gload_lds16(Bbase + (size_t)srow        * (K_TOT * 2) + kb, (char*)Bs + srow * 64 + skb);
    gload_lds16(Bbase + (size_t)(srow + 64) * (K_TOT * 2) + kb, (char*)Bs + (srow + 64) * 64 + skb);
    __syncthreads();  // staging visible (barrier drains vmcnt)

    short8 a[4], bb[4];
    #pragma unroll
    for (int i = 0; i < 4; ++i)
      a[i] = *(const short8*)((const char*)As + (wm + i * 16 + lr) * 64 + lg * 16);
    #pragma unroll
    for (int j = 0; j < 4; ++j)
      bb[j] = *(const short8*)((const char*)Bs + (wn + j * 16 + lr) * 64 + lg * 16);
    #pragma unroll
    for (int i = 0; i < 4; ++i)
      #pragma unroll
      for (int j = 0; j < 4; ++j)
        acc[i][j] = __builtin_amdgcn_mfma_f32_16x16x32_bf16(a[i], bb[j], acc[i][j], 0, 0, 0);
  }

  // epilogue: chunk is block-uniform (BN=128 divides 1024)
  const int chunk = n0 >> 10;
  #pragma unroll
  for (int j = 0; j < 4; ++j) {
    const int col = n0 + wn + j * 16 + lr;
    const int h   = col & (H_DIM - 1);
    const float bj = bias[col];
    #pragma unroll
    for (int i = 0; i < 4; ++i) {
      const int rbase = m0 + wm + i * 16 + lg * 4;
      #pragma unroll
      for (int r = 0; r < 4; ++r) {
        const float y = acc[i][j][r] + bj;
        const size_t idx = (size_t)(rbase + r) * H_DIM + h;
        if (chunk == 0) {
          wsZ[idx] = f2bfbits(tanhf_fast(y));
        } else if (chunk == 1) {
          wsF[idx] = f2bfbits(sigmoidf_fast(y));
        } else {
          wsO[idx] = f2bfbits(sigmoidf_fast(y));
        }
      }
    }
  }
}

// ---------- blocked scan pass 1: per-chunk (prod F, acc from 0) ----------
__global__ void scan_pass1(const __hip_bfloat16* __restrict__ F,
                           const __hip_bfloat16* __restrict__ Z,
                           float* __restrict__ chP, float* __restrict__ chA) {
  int t  = blockIdx.x * 256 + threadIdx.x;  // 0 .. NCHUNK*NCH-1
  int ch = t & (NCH - 1);
  int c  = t >> 14;
  size_t base = (size_t)c * CLEN * NCH + ch;
  float P = 1.f, A = 0.f;
  #pragma unroll 8
  for (int i = 0; i < CLEN; ++i) {
    float f = __bfloat162float(F[base + (size_t)i * NCH]);
    float z = __bfloat162float(Z[base + (size_t)i * NCH]);
    A = fmaf(f, A, (1.f - f) * z);
    P *= f;
  }
  chP[t] = P;
  chA[t] = A;
}

// ---------- mid scan: sequential over 32 chunks per channel ----------
__global__ void scan_mid(const float* __restrict__ chP, const float* __restrict__ chA,
                         const float* __restrict__ hidden,
                         float* __restrict__ Cst, float* __restrict__ outLast) {
  int ch = blockIdx.x * 256 + threadIdx.x;  // 0..16383
  float c0 = hidden[ch];
  #pragma unroll
  for (int c = 0; c < NCHUNK; ++c) {
    Cst[c * NCH + ch] = c0;
    c0 = fmaf(chP[c * NCH + ch], c0, chA[c * NCH + ch]);
  }
  outLast[ch] = c0;  // C[S-1] output (fp32)
}

// ---------- pass 2: recompute within chunk with correct start, fuse Hout ----------
__global__ void scan_pass2(const __hip_bfloat16* __restrict__ F,
                           const __hip_bfloat16* __restrict__ Z,
                           const __hip_bfloat16* __restrict__ O,
                           const float* __restrict__ Cst,
                           float* __restrict__ out) {
  int t  = blockIdx.x * 256 + threadIdx.x;
  int ch = t & (NCH - 1);
  int c  = t >> 14;
  float C = Cst[c * NCH + ch];
  size_t base = (size_t)c * CLEN * NCH + ch;
  #pragma unroll 8
  for (int i = 0; i < CLEN; ++i) {
    size_t idx = base + (size_t)i * NCH;
    float f = __bfloat162float(F[idx]);
    float z = __bfloat162float(Z[idx]);
    C = fmaf(f, C, (1.f - f) * z);
    out[idx] = __bfloat162float(O[idx]) * C;
  }
}

extern "C" void kernel_launch(void* const* d_in, const int* in_sizes, int n_in,
                              void* d_out, int out_size, void* d_ws, size_t ws_size,
                              hipStream_t stream) {
  const float* X      = (const float*)d_in[0];  // [S,B,D]
  const float* hidden = (const float*)d_in[1];  // [B,H]
  const float* W      = (const float*)d_in[2];  // [3H,D]
  const float* bias   = (const float*)d_in[3];  // [3H]
  float* out = (float*)d_out;                   // Hout [S,B,H] then C_last [1,B,H]

  char* ws = (char*)d_ws;
  // ws layout (bytes):
  __hip_bfloat16* Xb  = (__hip_bfloat16*)(ws);                 // 67,108,864
  __hip_bfloat16* Wb  = (__hip_bfloat16*)(ws + 67108864);      //  6,291,456
  unsigned short* wsZ = (unsigned short*)(ws + 73400320);      // 67,108,864 (bf16 bits)
  unsigned short* wsF = (unsigned short*)(ws + 140509184);     // 67,108,864
  unsigned short* wsO = (unsigned short*)(ws + 207618048);     // 67,108,864
  float* chP = (float*)(ws + 274726912);                       //  2,097,152
  float* chA = (float*)(ws + 276824064);                       //  2,097,152
  float* Cst = (float*)(ws + 278921216);                       //  2,097,152  (end ~281 MB)

  // 1) convert X and W to bf16
  cvt_kernel<<<(M_TOT * K_TOT / 4 + 255) / 256, 256, 0, stream>>>(X, (unsigned short*)Xb, M_TOT * K_TOT / 4);
  cvt_kernel<<<(N_TOT * K_TOT / 4 + 255) / 256, 256, 0, stream>>>(W, (unsigned short*)Wb, N_TOT * K_TOT / 4);

  // 2) fused GEMM + bias + activations
  gemm_act<<<NWG, 256, 0, stream>>>(Xb, Wb, bias, wsZ, wsF, wsO);

  // 3) blocked linear scan
  scan_pass1<<<(NCHUNK * NCH) / 256, 256, 0, stream>>>(
      (const __hip_bfloat16*)wsF, (const __hip_bfloat16*)wsZ, chP, chA);
  scan_mid<<<NCH / 256, 256, 0, stream>>>(chP, chA, hidden, Cst, out + (size_t)M_TOT * H_DIM);
  scan_pass2<<<(NCHUNK * NCH) / 256, 256, 0, stream>>>(
      (const __hip_bfloat16*)wsF, (const __hip_bfloat16*)wsZ,
      (const __hip_bfloat16*)wsO, Cst, out);
}

// Round 2
// 400.827 us; speedup vs baseline: 1.1343x; 1.1343x over previous
//
#include <hip/hip_runtime.h>
#include <hip/hip_bf16.h>
#include <stdint.h>

#define S_LEN 2048
#define B_SZ  16
#define D_DIM 1024
#define H_DIM 1024
#define M_TOT (S_LEN * B_SZ)      // 32768
#define N_TOT (3 * H_DIM)         // 3072
#define K_TOT D_DIM               // 1024

// ---- GEMM geometry: 256x256 tile, BK=64, 8 waves (2Mx4N), counted vmcnt ----
#define BM 256
#define BN 256
#define BK 64
#define NT   (K_TOT / BK)         // 16 K-tiles
#define NTN  (N_TOT / BN)         // 12
#define NWG  ((M_TOT / BM) * NTN) // 1536 (divisible by 8 -> simple XCD swizzle)

#define NCHUNK 32
#define CLEN   64                 // NCHUNK*CLEN == S_LEN
#define NCH    (B_SZ * H_DIM)     // 16384 independent channels

typedef __attribute__((ext_vector_type(8))) short short8;
typedef __attribute__((ext_vector_type(4))) float f32x4;

// ---------- helpers ----------
__device__ __forceinline__ void gload_lds16(const void* g, void* l) {
  __builtin_amdgcn_global_load_lds((__attribute__((address_space(1))) void*)g,
                                   (__attribute__((address_space(3))) void*)l,
                                   16, 0, 0);
}

__device__ __forceinline__ unsigned short f2bfbits(float x) {
  union { __hip_bfloat16 h; unsigned short u; } cv;
  cv.h = __float2bfloat16(x);
  return cv.u;
}

__device__ __forceinline__ float sigmoidf_fast(float y) {
  return 1.f / (1.f + __expf(-y));
}

__device__ __forceinline__ float tanhf_fast(float y) {
  float ay = fabsf(y);
  float e  = __expf(-2.f * ay);
  float t  = (1.f - e) / (1.f + e);
  return copysignf(t, y);
}

// ---------- fp32 -> bf16 conversion (vectorized) ----------
__global__ void cvt_kernel(const float* __restrict__ in,
                           unsigned short* __restrict__ out, int n4) {
  int i = blockIdx.x * 256 + threadIdx.x;
  if (i < n4) {
    float4 v = ((const float4*)in)[i];
    ushort4 o;
    o.x = f2bfbits(v.x); o.y = f2bfbits(v.y);
    o.z = f2bfbits(v.z); o.w = f2bfbits(v.w);
    ((ushort4*)out)[i] = o;
  }
}

// ---------- GEMM: Y = Xb * Wb^T + bias, fused activations ----------
// Counted-vmcnt schedule: stage tile t+1 (8 gload_lds/wave) at top of iter t,
// s_waitcnt vmcnt(8) lands tile t while t+1 stays in flight across all 4
// compute phases. T2 slot-XOR swizzle on LDS tiles, T5 setprio around MFMA.
__global__ __launch_bounds__(512, 2) void gemm_act(
    const __hip_bfloat16* __restrict__ Xb,
    const __hip_bfloat16* __restrict__ Wb,
    const float* __restrict__ bias,
    unsigned short* __restrict__ wsZ,
    unsigned short* __restrict__ wsF,
    unsigned short* __restrict__ wsO) {
  // [2 dbuf][256 rows][64 cols] bf16 for A at 0, B at 65536. 128 KiB total.
  __shared__ __align__(16) char lds[131072];

  int bid = blockIdx.x;
  int swz = (bid & 7) * (NWG >> 3) + (bid >> 3);   // XCD-aware, bijective
  int tm  = swz / NTN;
  int tn  = swz - tm * NTN;
  const int m0 = tm * BM;
  const int n0 = tn * BN;

  const int tid  = threadIdx.x;
  const int lane = tid & 63;
  const int wid  = tid >> 6;
  const int wr   = wid >> 2;        // 0..1 : wave row  (128 rows each)
  const int wc   = wid & 3;         // 0..3 : wave col  (64 cols each)
  const int lr   = lane & 15;
  const int lg   = lane >> 4;

  // staging coords: thread covers 16B; 64 rows per call (512 thr * 16B = 8KB)
  const int srow  = tid >> 3;       // 0..63
  const int sslot = tid & 7;        // 16B slot within 128B row

  const char* Ab = (const char*)(Xb + (size_t)m0 * K_TOT);
  const char* Bb = (const char*)(Wb + (size_t)n0 * K_TOT);

  f32x4 acc[8][4];
  const f32x4 vz = {0.f, 0.f, 0.f, 0.f};
  #pragma unroll
  for (int m = 0; m < 8; ++m)
    #pragma unroll
    for (int n = 0; n < 4; ++n) acc[m][n] = vz;

  // ---- stage K-tile t into buf[t&1]; source pre-swizzled (involution) ----
  #define STAGE(t)                                                            \
    {                                                                         \
      const size_t kb = (size_t)(t) * (BK * 2);                               \
      char* la = lds + ((t) & 1) * 32768;                                     \
      char* lb = lds + 65536 + ((t) & 1) * 32768;                             \
      _Pragma("unroll")                                                       \
      for (int h = 0; h < 4; ++h) {                                           \
        int r = h * 64 + srow;                                                \
        gload_lds16(Ab + (size_t)r * (K_TOT * 2) + kb + ((sslot ^ (r & 7)) << 4), \
                    la + r * 128 + (sslot << 4));                             \
      }                                                                       \
      _Pragma("unroll")                                                       \
      for (int h = 0; h < 4; ++h) {                                           \
        int r = h * 64 + srow;                                                \
        gload_lds16(Bb + (size_t)r * (K_TOT * 2) + kb + ((sslot ^ (r & 7)) << 4), \
                    lb + r * 128 + (sslot << 4));                             \
      }                                                                       \
    }

  STAGE(0);

  for (int t = 0; t < NT; ++t) {
    if (t + 1 < NT) {
      STAGE(t + 1);
      asm volatile("s_waitcnt vmcnt(8)" ::: "memory");  // tile t landed; t+1 in flight
    } else {
      asm volatile("s_waitcnt vmcnt(0)" ::: "memory");  // last tile: drain
    }
    __builtin_amdgcn_s_barrier();   // all waves certified their slices

    const char* la = lds + (t & 1) * 32768;
    const char* lb = lds + 65536 + (t & 1) * 32768;

    // B fragments: whole tile's worth, once per K-tile (8 x ds_read_b128)
    short8 bfr[4][2];
    #pragma unroll
    for (int n = 0; n < 4; ++n)
      #pragma unroll
      for (int ks = 0; ks < 2; ++ks) {
        int row = wc * 64 + n * 16 + lr;
        bfr[n][ks] = *(const short8*)(lb + row * 128 + ((((ks << 2) | lg) ^ (row & 7)) << 4));
      }

    // 4 phases: m-quadrant q -> 4 A ds_reads + 16 MFMA
    #pragma unroll
    for (int q = 0; q < 4; ++q) {
      short8 afr[2][2];
      #pragma unroll
      for (int mm = 0; mm < 2; ++mm)
        #pragma unroll
        for (int ks = 0; ks < 2; ++ks) {
          int row = wr * 128 + (q * 2 + mm) * 16 + lr;
          afr[mm][ks] = *(const short8*)(la + row * 128 + ((((ks << 2) | lg) ^ (row & 7)) << 4));
        }
      __builtin_amdgcn_s_setprio(1);
      #pragma unroll
      for (int ks = 0; ks < 2; ++ks)
        #pragma unroll
        for (int mm = 0; mm < 2; ++mm)
          #pragma unroll
          for (int n = 0; n < 4; ++n)
            acc[q * 2 + mm][n] = __builtin_amdgcn_mfma_f32_16x16x32_bf16(
                afr[mm][ks], bfr[n][ks], acc[q * 2 + mm][n], 0, 0, 0);
      __builtin_amdgcn_s_setprio(0);
      asm volatile("" ::: "memory");
      __builtin_amdgcn_s_barrier();  // phase-lock (last one also guards next STAGE)
    }
  }

  // ---- epilogue: bias + activation -> bf16 -> LDS (own wave region) ----
  // -> coalesced 16B global stores (full 128B per row segment).
  const int chunk = n0 >> 10;                 // block-uniform (BN=256 | 1024)
  const int hbase = (n0 & (H_DIM - 1)) + wc * 64;
  unsigned short* dst = (chunk == 0) ? wsZ : (chunk == 1) ? wsF : wsO;

  char* ep = lds + wid * 16384;               // 128 rows x 64 cols bf16
  float bv[4];
  #pragma unroll
  for (int n = 0; n < 4; ++n) bv[n] = bias[n0 + wc * 64 + n * 16 + lr];

  #pragma unroll
  for (int m = 0; m < 8; ++m)
    #pragma unroll
    for (int n = 0; n < 4; ++n)
      #pragma unroll
      for (int r = 0; r < 4; ++r) {
        float y = acc[m][n][r] + bv[n];
        float v = (chunk == 0) ? tanhf_fast(y) : sigmoidf_fast(y);
        int rowl = m * 16 + lg * 4 + r;       // 0..127
        *(unsigned short*)(ep + rowl * 128 + ((n * 16 + lr) << 1)) = f2bfbits(v);
      }

  // same-wave LDS readback (compiler inserts lgkmcnt for the alias)
  #pragma unroll
  for (int it = 0; it < 16; ++it) {
    int rl = it * 8 + (lane >> 3);
    short8 v = *(const short8*)(ep + rl * 128 + ((lane & 7) << 4));
    size_t grow = (size_t)(m0 + wr * 128 + rl);
    *(short8*)((char*)dst + (grow * H_DIM + hbase) * 2 + ((lane & 7) << 4)) = v;
  }
}

// ---------- blocked scan pass 1: per-chunk (prod F, acc from 0) ----------
__global__ void scan_pass1(const __hip_bfloat16* __restrict__ F,
                           const __hip_bfloat16* __restrict__ Z,
                           float* __restrict__ chP, float* __restrict__ chA) {
  int t  = blockIdx.x * 256 + threadIdx.x;  // 0 .. NCHUNK*NCH-1
  int ch = t & (NCH - 1);
  int c  = t >> 14;
  size_t base = (size_t)c * CLEN * NCH + ch;
  float P = 1.f, A = 0.f;
  #pragma unroll 8
  for (int i = 0; i < CLEN; ++i) {
    float f = __bfloat162float(F[base + (size_t)i * NCH]);
    float z = __bfloat162float(Z[base + (size_t)i * NCH]);
    A = fmaf(f, A, (1.f - f) * z);
    P *= f;
  }
  chP[t] = P;
  chA[t] = A;
}

// ---------- mid scan: sequential over 32 chunks per channel ----------
__global__ void scan_mid(const float* __restrict__ chP, const float* __restrict__ chA,
                         const float* __restrict__ hidden,
                         float* __restrict__ Cst, float* __restrict__ outLast) {
  int ch = blockIdx.x * 256 + threadIdx.x;  // 0..16383
  float c0 = hidden[ch];
  #pragma unroll
  for (int c = 0; c < NCHUNK; ++c) {
    Cst[c * NCH + ch] = c0;
    c0 = fmaf(chP[c * NCH + ch], c0, chA[c * NCH + ch]);
  }
  outLast[ch] = c0;  // C[S-1] output (fp32)
}

// ---------- pass 2: recompute within chunk with correct start, fuse Hout ----------
__global__ void scan_pass2(const __hip_bfloat16* __restrict__ F,
                           const __hip_bfloat16* __restrict__ Z,
                           const __hip_bfloat16* __restrict__ O,
                           const float* __restrict__ Cst,
                           float* __restrict__ out) {
  int t  = blockIdx.x * 256 + threadIdx.x;
  int ch = t & (NCH - 1);
  int c  = t >> 14;
  float C = Cst[c * NCH + ch];
  size_t base = (size_t)c * CLEN * NCH + ch;
  #pragma unroll 8
  for (int i = 0; i < CLEN; ++i) {
    size_t idx = base + (size_t)i * NCH;
    float f = __bfloat162float(F[idx]);
    float z = __bfloat162float(Z[idx]);
    C = fmaf(f, C, (1.f - f) * z);
    out[idx] = __bfloat162float(O[idx]) * C;
  }
}

extern "C" void kernel_launch(void* const* d_in, const int* in_sizes, int n_in,
                              void* d_out, int out_size, void* d_ws, size_t ws_size,
                              hipStream_t stream) {
  const float* X      = (const float*)d_in[0];  // [S,B,D]
  const float* hidden = (const float*)d_in[1];  // [B,H]
  const float* W      = (const float*)d_in[2];  // [3H,D]
  const float* bias   = (const float*)d_in[3];  // [3H]
  float* out = (float*)d_out;                   // Hout [S,B,H] then C_last [1,B,H]

  char* ws = (char*)d_ws;
  __hip_bfloat16* Xb  = (__hip_bfloat16*)(ws);                 // 67,108,864
  __hip_bfloat16* Wb  = (__hip_bfloat16*)(ws + 67108864);      //  6,291,456
  unsigned short* wsZ = (unsigned short*)(ws + 73400320);      // 67,108,864 (bf16 bits)
  unsigned short* wsF = (unsigned short*)(ws + 140509184);     // 67,108,864
  unsigned short* wsO = (unsigned short*)(ws + 207618048);     // 67,108,864
  float* chP = (float*)(ws + 274726912);                       //  2,097,152
  float* chA = (float*)(ws + 276824064);                       //  2,097,152
  float* Cst = (float*)(ws + 278921216);                       //  2,097,152

  // 1) convert X and W to bf16
  cvt_kernel<<<(M_TOT * K_TOT / 4 + 255) / 256, 256, 0, stream>>>(X, (unsigned short*)Xb, M_TOT * K_TOT / 4);
  cvt_kernel<<<(N_TOT * K_TOT / 4 + 255) / 256, 256, 0, stream>>>(W, (unsigned short*)Wb, N_TOT * K_TOT / 4);

  // 2) fused GEMM + bias + activations (256^2 tile, counted vmcnt)
  gemm_act<<<NWG, 512, 0, stream>>>(Xb, Wb, bias, wsZ, wsF, wsO);

  // 3) blocked linear scan
  scan_pass1<<<(NCHUNK * NCH) / 256, 256, 0, stream>>>(
      (const __hip_bfloat16*)wsF, (const __hip_bfloat16*)wsZ, chP, chA);
  scan_mid<<<NCH / 256, 256, 0, stream>>>(chP, chA, hidden, Cst, out + (size_t)M_TOT * H_DIM);
  scan_pass2<<<(NCHUNK * NCH) / 256, 256, 0, stream>>>(
      (const __hip_bfloat16*)wsF, (const __hip_bfloat16*)wsZ,
      (const __hip_bfloat16*)wsO, Cst, out);
}